// Round 7
// baseline (203.413 us; speedup 1.0000x reference)
//
#include <hip/hip_runtime.h>
#include <math.h>

#define NB   8
#define BC   32
#define WIN  14
#define HH   16
#define BKK  288     // 32*3*3
#define CWW  1152    // 32*6*6
#define NXY  36
#define NBLK 1152    // 8 b x 36 xy x 4 cquarter
#define PSTR 1152    // psum stride per m = NXY*32
#define EPSF 1e-10f
#define LOG2E 1.4426950408889634f
#define LN2   0.6931471805599453f
#define L2SQ2PI 1.3257480647361593f  // log2(sqrt(2*pi))

__device__ __forceinline__ float ex2(float x) { return __builtin_amdgcn_exp2f(x); }
__device__ __forceinline__ float lg2(float x) { return __builtin_amdgcn_logf(x); }
__device__ __forceinline__ float rcpf(float x) { return __builtin_amdgcn_rcpf(x); }

__device__ __forceinline__ float red16(float v) {
    v += __shfl_xor(v, 1);
    v += __shfl_xor(v, 2);
    v += __shfl_xor(v, 4);
    v += __shfl_xor(v, 8);
    return v;
}

__device__ __forceinline__ float4 f4mul(float s, float4 b) {
    return make_float4(s * b.x, s * b.y, s * b.z, s * b.w);
}
__device__ __forceinline__ float4 f4fma(float s, float4 b, float4 c) {
    return make_float4(fmaf(s, b.x, c.x), fmaf(s, b.y, c.y),
                       fmaf(s, b.z, c.z), fmaf(s, b.w, c.w));
}

// W[m][c][p][q] (float4 rows over q) -> Wt[m][p][c] (float4 over q).
// Writes a zeroed slack row (m=288) for the prefetch rotation; zero-inits
// rows0/rows1 (atomicAdd accumulators; ws is poisoned each launch).
__global__ __launch_bounds__(256)
void wt_kernel(const float4* __restrict__ W4, float4* __restrict__ Wt4,
               float* __restrict__ rowsZ) {
    int o = blockIdx.x * 256 + threadIdx.x;   // 288*4*32 = 36864
    if (o < 2 * NB * BKK) rowsZ[o] = 0.0f;
    if (o < 128) Wt4[BKK * 128 + o] = make_float4(0.f, 0.f, 0.f, 0.f);  // slack row
    if (o < BKK * 128) {
        int c = o & 31, p = (o >> 5) & 3, m = o >> 7;
        Wt4[o] = W4[(m * 32 + c) * 4 + p];
    }
}

// ---------------------------------------------------------------------------
// One EM stage: stats(it) [+ pv(it) when !FINAL]. 1152 blocks = (b, xy, cq),
// b = bid&7 (XCD swizzle), 256 thr = 8 c x 32 mchunks (9 m each).
// Cross-iteration sync = dispatch boundary (no co-residency requirement);
// psum crosses stages via global (L2-resident per XCD); row sums via
// agent-scope fp32 atomicAdd (written stage N, plain-read stage N+1).
// LDS ~27 KB, launch_bounds(256,4) => VGPR<=128, 4 blocks/CU, ~50% occ.
// ---------------------------------------------------------------------------
template<int IT, bool FINAL>
__global__ __launch_bounds__(256, 4)
void em_stage(const float* __restrict__ poses,
              const float* __restrict__ act,
              const float4* __restrict__ Wt4,
              const float* __restrict__ beta_v,
              const float* __restrict__ beta_a,
              const float* __restrict__ lam,
              const float* __restrict__ rows_in,   // [b][288] (IT>=1)
              float* __restrict__ rows_out,        // [b][288] (!FINAL)
              const float* __restrict__ aws_in,    // [b][xy][32] (IT>=1)
              float* __restrict__ aws_out,         // [b][xy][32] (!FINAL)
              float* __restrict__ psum,            // [b][m][xy][32] (+slack)
              float* __restrict__ mu_out,          // [b][n][16] (FINAL)
              float* __restrict__ a_out)           // [b][n]     (FINAL)
{
    __shared__ float4 poseS4[BKK * 4];                 // 18432 B
    __shared__ float2 AE[BKK];                         //  2304 B (am*invR, EPS*am)
    __shared__ float  muL[8][16];                      //   512 B
    __shared__ float  KL[8][16];
    __shared__ float  CL[8][16];
    __shared__ float  aL[8];                           //    32 B
    __shared__ __align__(16) float4 red4[4 * 8 * 9];   //  4608 B

    const int bid = blockIdx.x;             // 1152
    const int b   = bid & 7;                // XCD swizzle: batch <-> XCD
    const int idx = bid >> 3;               // 0..143
    const int cq  = idx & 3;                // c quarter
    const int xy  = idx >> 2;               // 0..35
    const int X = xy / 6, Y = xy % 6;

    const int tid = threadIdx.x;
    const int c_l = tid & 7;                // 0..7
    const int mch = tid >> 3;               // 0..31
    const int c   = cq * 8 + c_l;
    const int m0  = mch * 9;

    const float4* poses4 = reinterpret_cast<const float4*>(poses);
    for (int i2 = tid; i2 < BKK * 4; i2 += 256) {
        int m = i2 >> 2, q = i2 & 3;
        int B = m / 9, uv = m % 9, u = uv / 3, v = uv % 3;
        poseS4[i2] = poses4[((b * BC + B) * 196 + (2 * Y + u) * WIN + (2 * X + v)) * 4 + q];
    }
    for (int m = tid; m < BKK; m += 256) {
        int B = m / 9, uv = m % 9, u = uv / 3, v = uv % 3;
        float am = act[(b * BC + B) * 196 + (2 * Y + u) * WIN + (2 * X + v)];
        if constexpr (IT == 0) {
            AE[m] = make_float2(am * (1.0f / 32.0f), 0.0f);    // R = 1/32
        } else {
            float s = rows_in[b * BKK + m];
            AE[m] = make_float2(am / (s + EPSF), EPSF * am);
        }
    }
    __syncthreads();

    const float4* WtB  = Wt4 + c;           // + m*128 + p*32
    const float   lamv = lam[0];
    const float*  redF = reinterpret_cast<const float*>(red4);
    float* psp = psum + ((b * BKK + m0) * NXY + xy) * 32 + c;   // + i*PSTR

    float ap_n = 0.0f;
    if constexpr (IT >= 1) ap_n = aws_in[(b * NXY + xy) * 32 + c];

    // ========================= stats =========================
    float  sum_R = 0.0f;
    float4 sRV[4]  = {make_float4(0,0,0,0), make_float4(0,0,0,0),
                      make_float4(0,0,0,0), make_float4(0,0,0,0)};
    float4 sRV2[4] = {make_float4(0,0,0,0), make_float4(0,0,0,0),
                      make_float4(0,0,0,0), make_float4(0,0,0,0)};
    {
        const float4* wp = WtB + m0 * 128;
        float4 w0 = wp[0], w1 = wp[32], w2 = wp[64], w3 = wp[96];
        const float* pp = psp;
        float ps_c = 0.0f;
        if constexpr (IT >= 1) ps_c = pp[0];
        #pragma unroll 1
        for (int i = 0; i < 9; ++i) {
            const int m = m0 + i;
            wp += 128;                               // i=8 -> slack row 288
            float4 nw0 = wp[0], nw1 = wp[32], nw2 = wp[64], nw3 = wp[96];
            float ps_n = 0.0f;
            if constexpr (IT >= 1) { pp += PSTR; ps_n = pp[0]; }   // i=8 -> slack
            float4 P0 = poseS4[m * 4 + 0];
            float4 P1 = poseS4[m * 4 + 1];
            float4 P2 = poseS4[m * 4 + 2];
            float4 P3 = poseS4[m * 4 + 3];
            float4 V0 = f4fma(w0.w, P3, f4fma(w0.z, P2, f4fma(w0.y, P1, f4mul(w0.x, P0))));
            float4 V1 = f4fma(w1.w, P3, f4fma(w1.z, P2, f4fma(w1.y, P1, f4mul(w1.x, P0))));
            float4 V2 = f4fma(w2.w, P3, f4fma(w2.z, P2, f4fma(w2.y, P1, f4mul(w2.x, P0))));
            float4 V3 = f4fma(w3.w, P3, f4fma(w3.z, P2, f4fma(w3.y, P1, f4mul(w3.x, P0))));
            float2 ae = AE[m];
            float Ra;
            if constexpr (IT == 0) Ra = ae.x;
            else                   Ra = fmaf(ap_n * ps_c, ae.x, ae.y);
            sum_R += Ra;
            sRV[0] = f4fma(Ra, V0, sRV[0]);
            sRV[1] = f4fma(Ra, V1, sRV[1]);
            sRV[2] = f4fma(Ra, V2, sRV[2]);
            sRV[3] = f4fma(Ra, V3, sRV[3]);
            float4 q0 = make_float4(V0.x*V0.x, V0.y*V0.y, V0.z*V0.z, V0.w*V0.w);
            float4 q1 = make_float4(V1.x*V1.x, V1.y*V1.y, V1.z*V1.z, V1.w*V1.w);
            float4 q2 = make_float4(V2.x*V2.x, V2.y*V2.y, V2.z*V2.z, V2.w*V2.w);
            float4 q3 = make_float4(V3.x*V3.x, V3.y*V3.y, V3.z*V3.z, V3.w*V3.w);
            sRV2[0] = f4fma(Ra, q0, sRV2[0]);
            sRV2[1] = f4fma(Ra, q1, sRV2[1]);
            sRV2[2] = f4fma(Ra, q2, sRV2[2]);
            sRV2[3] = f4fma(Ra, q3, sRV2[3]);
            w0 = nw0; w1 = nw1; w2 = nw2; w3 = nw3;
            ps_c = ps_n;
        }
    }

    // combine the 8 mchunk subgroups within each wave (lane bits 3,4,5)
    {
        float* f1 = reinterpret_cast<float*>(sRV);
        float* f2 = reinterpret_cast<float*>(sRV2);
        #pragma unroll
        for (int k = 0; k < 16; ++k) { f1[k] += __shfl_xor(f1[k], 8);  f2[k] += __shfl_xor(f2[k], 8); }
        sum_R += __shfl_xor(sum_R, 8);
        #pragma unroll
        for (int k = 0; k < 16; ++k) { f1[k] += __shfl_xor(f1[k], 16); f2[k] += __shfl_xor(f2[k], 16); }
        sum_R += __shfl_xor(sum_R, 16);
        #pragma unroll
        for (int k = 0; k < 16; ++k) { f1[k] += __shfl_xor(f1[k], 32); f2[k] += __shfl_xor(f2[k], 32); }
        sum_R += __shfl_xor(sum_R, 32);
    }
    if ((tid & 56) == 0) {                  // lanes 0..7 of each wave
        float4* dst = &red4[((tid >> 6) * 8 + c_l) * 9];
        dst[0] = make_float4(sum_R, 0.f, 0.f, 0.f);
        dst[1] = sRV[0];  dst[2] = sRV[1];  dst[3] = sRV[2];  dst[4] = sRV[3];
        dst[5] = sRV2[0]; dst[6] = sRV2[1]; dst[7] = sRV2[2]; dst[8] = sRV2[3];
    }
    __syncthreads();

    // -------- epilogue: thread = (h, cc), cc<8 active --------
    {
        const int h  = tid & 15;
        const int cc = tid >> 4;
        if (cc < 8) {
            float sR = 0.f, sV = 0.f, sV2 = 0.f;
            #pragma unroll
            for (int j = 0; j < 4; ++j) {
                int off = (j * 8 + cc) * 36;
                sR  += redF[off];
                sV  += redF[off + 4 + h];
                sV2 += redF[off + 20 + h];
            }
            float inv = 1.0f / sR;
            float mu  = sV * inv;
            float sig = fmaxf(fmaf(-mu, mu, sV2 * inv), 1e-30f);
            float l2s = lg2(sqrtf(sig) + EPSF);          // log2(sigma+eps)
            float lsum = red16(l2s) * LN2;               // sum_h ln(sigma)
            int   cgi  = cq * 8 + cc;
            float cost = sR * fmaf(16.0f, beta_v[cgi], lsum);
            float z    = lamv * (beta_a[cgi] - cost);
            float av   = rcpf(1.0f + ex2(-z * LOG2E));
            if constexpr (FINAL) {
                int nn   = cgi * NXY + xy;
                int base = (b * CWW + nn) * HH + h;
                mu_out[base] = mu;
                if (h == 0) a_out[b * CWW + nn] = av;
            } else {
                muL[cc][h] = mu;
                KL[cc][h]  = (-0.5f * LOG2E) / sig;
                CL[cc][h]  = -(l2s + L2SQ2PI);
                if (h == 0) {
                    aL[cc] = av;
                    aws_out[(b * NXY + xy) * 32 + cgi] = av;
                }
            }
        }
    }

    if constexpr (!FINAL) {
        __syncthreads();                    // muL/KL/CL/aL visible

        // ========================= pv =========================
        float4 M[4], Kk[4], Cc[4];
        #pragma unroll
        for (int p = 0; p < 4; ++p) {
            M[p]  = make_float4(muL[c_l][4*p+0], muL[c_l][4*p+1], muL[c_l][4*p+2], muL[c_l][4*p+3]);
            Kk[p] = make_float4(KL[c_l][4*p+0],  KL[c_l][4*p+1],  KL[c_l][4*p+2],  KL[c_l][4*p+3]);
            Cc[p] = make_float4(CL[c_l][4*p+0],  CL[c_l][4*p+1],  CL[c_l][4*p+2],  CL[c_l][4*p+3]);
        }
        const float ap = aL[c_l];
        float* rowsO = rows_out + b * BKK;
        float* pw = psp;

        const float4* wp = WtB + m0 * 128;
        float4 w0 = wp[0], w1 = wp[32], w2 = wp[64], w3 = wp[96];
        #pragma unroll 1
        for (int i = 0; i < 9; ++i) {
            const int m = m0 + i;
            wp += 128;                               // i=8 -> slack row 288
            float4 nw0 = wp[0], nw1 = wp[32], nw2 = wp[64], nw3 = wp[96];
            float4 P0 = poseS4[m * 4 + 0];
            float4 P1 = poseS4[m * 4 + 1];
            float4 P2 = poseS4[m * 4 + 2];
            float4 P3 = poseS4[m * 4 + 3];
            float4 V0 = f4fma(w0.w, P3, f4fma(w0.z, P2, f4fma(w0.y, P1, f4mul(w0.x, P0))));
            float4 V1 = f4fma(w1.w, P3, f4fma(w1.z, P2, f4fma(w1.y, P1, f4mul(w1.x, P0))));
            float4 V2 = f4fma(w2.w, P3, f4fma(w2.z, P2, f4fma(w2.y, P1, f4mul(w2.x, P0))));
            float4 V3 = f4fma(w3.w, P3, f4fma(w3.z, P2, f4fma(w3.y, P1, f4mul(w3.x, P0))));

            float psv = 0.0f;
            {
                float4 t, g;
                t = make_float4(V0.x-M[0].x, V0.y-M[0].y, V0.z-M[0].z, V0.w-M[0].w);
                g = make_float4(fmaf(t.x*t.x, Kk[0].x, Cc[0].x), fmaf(t.y*t.y, Kk[0].y, Cc[0].y),
                                fmaf(t.z*t.z, Kk[0].z, Cc[0].z), fmaf(t.w*t.w, Kk[0].w, Cc[0].w));
                psv += ex2(g.x) + ex2(g.y) + ex2(g.z) + ex2(g.w);
                t = make_float4(V1.x-M[1].x, V1.y-M[1].y, V1.z-M[1].z, V1.w-M[1].w);
                g = make_float4(fmaf(t.x*t.x, Kk[1].x, Cc[1].x), fmaf(t.y*t.y, Kk[1].y, Cc[1].y),
                                fmaf(t.z*t.z, Kk[1].z, Cc[1].z), fmaf(t.w*t.w, Kk[1].w, Cc[1].w));
                psv += ex2(g.x) + ex2(g.y) + ex2(g.z) + ex2(g.w);
                t = make_float4(V2.x-M[2].x, V2.y-M[2].y, V2.z-M[2].z, V2.w-M[2].w);
                g = make_float4(fmaf(t.x*t.x, Kk[2].x, Cc[2].x), fmaf(t.y*t.y, Kk[2].y, Cc[2].y),
                                fmaf(t.z*t.z, Kk[2].z, Cc[2].z), fmaf(t.w*t.w, Kk[2].w, Cc[2].w));
                psv += ex2(g.x) + ex2(g.y) + ex2(g.z) + ex2(g.w);
                t = make_float4(V3.x-M[3].x, V3.y-M[3].y, V3.z-M[3].z, V3.w-M[3].w);
                g = make_float4(fmaf(t.x*t.x, Kk[3].x, Cc[3].x), fmaf(t.y*t.y, Kk[3].y, Cc[3].y),
                                fmaf(t.z*t.z, Kk[3].z, Cc[3].z), fmaf(t.w*t.w, Kk[3].w, Cc[3].w));
                psv += ex2(g.x) + ex2(g.y) + ex2(g.z) + ex2(g.w);
            }
            pw[0] = psv;                    // psum[(b,m,xy,c)]
            pw += PSTR;

            float rv = ap * psv;
            rv += __shfl_xor(rv, 1);
            rv += __shfl_xor(rv, 2);
            rv += __shfl_xor(rv, 4);
            if (c_l == 0)
                __hip_atomic_fetch_add(&rowsO[m], rv,
                                       __ATOMIC_RELAXED, __HIP_MEMORY_SCOPE_AGENT);
            w0 = nw0; w1 = nw1; w2 = nw2; w3 = nw3;
        }
    }
}

extern "C" void kernel_launch(void* const* d_in, const int* in_sizes, int n_in,
                              void* d_out, int out_size, void* d_ws, size_t ws_size,
                              hipStream_t stream) {
    const float* poses  = (const float*)d_in[0];
    const float* act    = (const float*)d_in[1];
    const float* W      = (const float*)d_in[2];
    const float* beta_v = (const float*)d_in[3];
    const float* beta_a = (const float*)d_in[4];
    const float* lam    = (const float*)d_in[5];
    float* out = (float*)d_out;
    float* ws  = (float*)d_ws;

    const int SZ = NB * CWW * HH;            // 147456
    float* Wt    = ws;                       // (288+1)*128 float4 = 147968 floats
    float* rows0 = Wt + 289 * 512;           // 2304
    float* rows1 = rows0 + NB * BKK;         // 2304
    float* aws0  = rows1 + NB * BKK;         // 9216
    float* aws1  = aws0 + NB * CWW;          // 9216
    float* psum  = aws1 + NB * CWW;          // 8*288*36*32 = 2654208 + 1152 slack
    // total ~2.83M floats = 11.3 MB of ws

    wt_kernel<<<dim3(144), dim3(256), 0, stream>>>(
        (const float4*)W, (float4*)Wt, rows0);

    const float4* Wt4 = (const float4*)Wt;
    em_stage<0, false><<<dim3(NBLK), dim3(256), 0, stream>>>(
        poses, act, Wt4, beta_v, beta_a, lam,
        nullptr, rows0, nullptr, aws0, psum, nullptr, nullptr);
    em_stage<1, false><<<dim3(NBLK), dim3(256), 0, stream>>>(
        poses, act, Wt4, beta_v, beta_a, lam,
        rows0, rows1, aws0, aws1, psum, nullptr, nullptr);
    em_stage<1, true><<<dim3(NBLK), dim3(256), 0, stream>>>(
        poses, act, Wt4, beta_v, beta_a, lam,
        rows1, nullptr, aws1, nullptr, psum, out, out + SZ);
}

// Round 8
// 199.533 us; speedup vs baseline: 1.0194x; 1.0194x over previous
//
#include <hip/hip_runtime.h>
#include <math.h>

#define NB   8
#define BC   32
#define WIN  14
#define HH   16
#define BKK  288     // 32*3*3
#define CWW  1152    // 32*6*6
#define NXY  36
#define NBLK 1152    // 8 b x 36 xy x 4 cquarter
#define PBLK 2304    // psum floats per block = 9*32*8
#define EPSF 1e-10f
#define LOG2E 1.4426950408889634f
#define LN2   0.6931471805599453f
#define L2SQ2PI 1.3257480647361593f  // log2(sqrt(2*pi))

__device__ __forceinline__ float ex2(float x) { return __builtin_amdgcn_exp2f(x); }
__device__ __forceinline__ float lg2(float x) { return __builtin_amdgcn_logf(x); }
__device__ __forceinline__ float rcpf(float x) { return __builtin_amdgcn_rcpf(x); }

__device__ __forceinline__ float red16(float v) {
    v += __shfl_xor(v, 1);
    v += __shfl_xor(v, 2);
    v += __shfl_xor(v, 4);
    v += __shfl_xor(v, 8);
    return v;
}

__device__ __forceinline__ float4 f4mul(float s, float4 b) {
    return make_float4(s * b.x, s * b.y, s * b.z, s * b.w);
}
__device__ __forceinline__ float4 f4fma(float s, float4 b, float4 c) {
    return make_float4(fmaf(s, b.x, c.x), fmaf(s, b.y, c.y),
                       fmaf(s, b.z, c.z), fmaf(s, b.w, c.w));
}

// W[m][c][p][q] (float4 rows over q) -> Wt[m][p][c] (float4 over q).
// Writes a zeroed slack row (m=288) for the prefetch rotation; zero-inits
// rows0/rows1 (atomicAdd accumulators; ws is poisoned each launch).
__global__ __launch_bounds__(256)
void wt_kernel(const float4* __restrict__ W4, float4* __restrict__ Wt4,
               float* __restrict__ rowsZ) {
    int o = blockIdx.x * 256 + threadIdx.x;   // 288*4*32 = 36864
    if (o < 2 * NB * BKK) rowsZ[o] = 0.0f;
    if (o < 128) Wt4[BKK * 128 + o] = make_float4(0.f, 0.f, 0.f, 0.f);  // slack row
    if (o < BKK * 128) {
        int c = o & 31, p = (o >> 5) & 3, m = o >> 7;
        Wt4[o] = W4[(m * 32 + c) * 4 + p];
    }
}

// ---------------------------------------------------------------------------
// One EM stage: stats(it) [+ pv(it) when !FINAL]. 1152 blocks = (b, xy, cq),
// b = bid&7 (XCD swizzle), 256 thr = 8 c x 32 mchunks (9 m each).
// Cross-iteration sync = dispatch boundary. psum is BLOCK-PRIVATE and fully
// coalesced: [blk][i][mch][c_l] -- stage N's block writes exactly what stage
// N+1's same block reads with the same thread mapping (256B/wave lines).
// poseS4 row stride padded 4->5 float4: the 8 mch's (m 9 apart) land on 8
// distinct bank groups -> conflict-free ds_read_b128.
// LDS ~31.5 KB -> 5 blocks/CU >= grid's 4.5; launch_bounds(256,4), VGPR ~52.
// ---------------------------------------------------------------------------
template<int IT, bool FINAL>
__global__ __launch_bounds__(256, 4)
void em_stage(const float* __restrict__ poses,
              const float* __restrict__ act,
              const float4* __restrict__ Wt4,
              const float* __restrict__ beta_v,
              const float* __restrict__ beta_a,
              const float* __restrict__ lam,
              const float* __restrict__ rows_in,   // [b][288] (IT>=1)
              float* __restrict__ rows_out,        // [b][288] (!FINAL)
              const float* __restrict__ aws_in,    // [b][xy][32] (IT>=1)
              float* __restrict__ aws_out,         // [b][xy][32] (!FINAL)
              float* __restrict__ psum,            // [1152][9][32][8] (+slack)
              float* __restrict__ mu_out,          // [b][n][16] (FINAL)
              float* __restrict__ a_out)           // [b][n]     (FINAL)
{
    __shared__ float4 poseS4[BKK * 5];                 // 23040 B (stride-5 pad)
    __shared__ float2 AE[BKK];                         //  2304 B (am*invR, EPS*am)
    __shared__ float  muL[8][16];                      //   512 B
    __shared__ float  KL[8][16];
    __shared__ float  CL[8][16];
    __shared__ float  aL[8];                           //    32 B
    __shared__ __align__(16) float4 red4[4 * 8 * 9];   //  4608 B

    const int bid = blockIdx.x;             // 1152
    const int b   = bid & 7;                // XCD swizzle: batch <-> XCD
    const int idx = bid >> 3;               // 0..143
    const int cq  = idx & 3;                // c quarter
    const int xy  = idx >> 2;               // 0..35
    const int X = xy / 6, Y = xy % 6;

    const int tid = threadIdx.x;
    const int c_l = tid & 7;                // 0..7
    const int mch = tid >> 3;               // 0..31
    const int c   = cq * 8 + c_l;
    const int m0  = mch * 9;

    const float4* poses4 = reinterpret_cast<const float4*>(poses);
    for (int i2 = tid; i2 < BKK * 4; i2 += 256) {
        int m = i2 >> 2, q = i2 & 3;
        int B = m / 9, uv = m % 9, u = uv / 3, v = uv % 3;
        poseS4[m * 5 + q] = poses4[((b * BC + B) * 196 + (2 * Y + u) * WIN + (2 * X + v)) * 4 + q];
    }
    for (int m = tid; m < BKK; m += 256) {
        int B = m / 9, uv = m % 9, u = uv / 3, v = uv % 3;
        float am = act[(b * BC + B) * 196 + (2 * Y + u) * WIN + (2 * X + v)];
        if constexpr (IT == 0) {
            AE[m] = make_float2(am * (1.0f / 32.0f), 0.0f);    // R = 1/32
        } else {
            float s = rows_in[b * BKK + m];
            AE[m] = make_float2(am / (s + EPSF), EPSF * am);
        }
    }
    __syncthreads();

    const float4* WtB  = Wt4 + c;           // + m*128 + p*32
    const float   lamv = lam[0];
    const float*  redF = reinterpret_cast<const float*>(red4);
    // block-private coalesced psum slice: + i*256 + mch*8 + c_l
    float* psp = psum + ((idx * 8 + b) * PBLK) + mch * 8 + c_l;

    float ap_n = 0.0f;
    if constexpr (IT >= 1) ap_n = aws_in[(b * NXY + xy) * 32 + c];

    // ========================= stats =========================
    float  sum_R = 0.0f;
    float4 sRV[4]  = {make_float4(0,0,0,0), make_float4(0,0,0,0),
                      make_float4(0,0,0,0), make_float4(0,0,0,0)};
    float4 sRV2[4] = {make_float4(0,0,0,0), make_float4(0,0,0,0),
                      make_float4(0,0,0,0), make_float4(0,0,0,0)};
    {
        const float4* wp = WtB + m0 * 128;
        float4 w0 = wp[0], w1 = wp[32], w2 = wp[64], w3 = wp[96];
        const float* pp = psp;
        float ps_c = 0.0f;
        if constexpr (IT >= 1) ps_c = pp[0];
        #pragma unroll 1
        for (int i = 0; i < 9; ++i) {
            const int m = m0 + i;
            wp += 128;                               // i=8 -> slack row 288
            float4 nw0 = wp[0], nw1 = wp[32], nw2 = wp[64], nw3 = wp[96];
            float ps_n = 0.0f;
            if constexpr (IT >= 1) { pp += 256; ps_n = pp[0]; }   // i=8 -> slack
            float4 P0 = poseS4[m * 5 + 0];
            float4 P1 = poseS4[m * 5 + 1];
            float4 P2 = poseS4[m * 5 + 2];
            float4 P3 = poseS4[m * 5 + 3];
            float4 V0 = f4fma(w0.w, P3, f4fma(w0.z, P2, f4fma(w0.y, P1, f4mul(w0.x, P0))));
            float4 V1 = f4fma(w1.w, P3, f4fma(w1.z, P2, f4fma(w1.y, P1, f4mul(w1.x, P0))));
            float4 V2 = f4fma(w2.w, P3, f4fma(w2.z, P2, f4fma(w2.y, P1, f4mul(w2.x, P0))));
            float4 V3 = f4fma(w3.w, P3, f4fma(w3.z, P2, f4fma(w3.y, P1, f4mul(w3.x, P0))));
            float2 ae = AE[m];
            float Ra;
            if constexpr (IT == 0) Ra = ae.x;
            else                   Ra = fmaf(ap_n * ps_c, ae.x, ae.y);
            sum_R += Ra;
            sRV[0] = f4fma(Ra, V0, sRV[0]);
            sRV[1] = f4fma(Ra, V1, sRV[1]);
            sRV[2] = f4fma(Ra, V2, sRV[2]);
            sRV[3] = f4fma(Ra, V3, sRV[3]);
            float4 q0 = make_float4(V0.x*V0.x, V0.y*V0.y, V0.z*V0.z, V0.w*V0.w);
            float4 q1 = make_float4(V1.x*V1.x, V1.y*V1.y, V1.z*V1.z, V1.w*V1.w);
            float4 q2 = make_float4(V2.x*V2.x, V2.y*V2.y, V2.z*V2.z, V2.w*V2.w);
            float4 q3 = make_float4(V3.x*V3.x, V3.y*V3.y, V3.z*V3.z, V3.w*V3.w);
            sRV2[0] = f4fma(Ra, q0, sRV2[0]);
            sRV2[1] = f4fma(Ra, q1, sRV2[1]);
            sRV2[2] = f4fma(Ra, q2, sRV2[2]);
            sRV2[3] = f4fma(Ra, q3, sRV2[3]);
            w0 = nw0; w1 = nw1; w2 = nw2; w3 = nw3;
            ps_c = ps_n;
        }
    }

    // combine the 8 mchunk subgroups within each wave (lane bits 3,4,5)
    {
        float* f1 = reinterpret_cast<float*>(sRV);
        float* f2 = reinterpret_cast<float*>(sRV2);
        #pragma unroll
        for (int k = 0; k < 16; ++k) { f1[k] += __shfl_xor(f1[k], 8);  f2[k] += __shfl_xor(f2[k], 8); }
        sum_R += __shfl_xor(sum_R, 8);
        #pragma unroll
        for (int k = 0; k < 16; ++k) { f1[k] += __shfl_xor(f1[k], 16); f2[k] += __shfl_xor(f2[k], 16); }
        sum_R += __shfl_xor(sum_R, 16);
        #pragma unroll
        for (int k = 0; k < 16; ++k) { f1[k] += __shfl_xor(f1[k], 32); f2[k] += __shfl_xor(f2[k], 32); }
        sum_R += __shfl_xor(sum_R, 32);
    }
    if ((tid & 56) == 0) {                  // lanes 0..7 of each wave
        float4* dst = &red4[((tid >> 6) * 8 + c_l) * 9];
        dst[0] = make_float4(sum_R, 0.f, 0.f, 0.f);
        dst[1] = sRV[0];  dst[2] = sRV[1];  dst[3] = sRV[2];  dst[4] = sRV[3];
        dst[5] = sRV2[0]; dst[6] = sRV2[1]; dst[7] = sRV2[2]; dst[8] = sRV2[3];
    }
    __syncthreads();

    // -------- epilogue: thread = (h, cc), cc<8 active --------
    {
        const int h  = tid & 15;
        const int cc = tid >> 4;
        if (cc < 8) {
            float sR = 0.f, sV = 0.f, sV2 = 0.f;
            #pragma unroll
            for (int j = 0; j < 4; ++j) {
                int off = (j * 8 + cc) * 36;
                sR  += redF[off];
                sV  += redF[off + 4 + h];
                sV2 += redF[off + 20 + h];
            }
            float inv = 1.0f / sR;
            float mu  = sV * inv;
            float sig = fmaxf(fmaf(-mu, mu, sV2 * inv), 1e-30f);
            float l2s = lg2(sqrtf(sig) + EPSF);          // log2(sigma+eps)
            float lsum = red16(l2s) * LN2;               // sum_h ln(sigma)
            int   cgi  = cq * 8 + cc;
            float cost = sR * fmaf(16.0f, beta_v[cgi], lsum);
            float z    = lamv * (beta_a[cgi] - cost);
            float av   = rcpf(1.0f + ex2(-z * LOG2E));
            if constexpr (FINAL) {
                int nn   = cgi * NXY + xy;
                int base = (b * CWW + nn) * HH + h;
                mu_out[base] = mu;
                if (h == 0) a_out[b * CWW + nn] = av;
            } else {
                muL[cc][h] = mu;
                KL[cc][h]  = (-0.5f * LOG2E) / sig;
                CL[cc][h]  = -(l2s + L2SQ2PI);
                if (h == 0) {
                    aL[cc] = av;
                    aws_out[(b * NXY + xy) * 32 + cgi] = av;
                }
            }
        }
    }

    if constexpr (!FINAL) {
        __syncthreads();                    // muL/KL/CL/aL visible

        // ========================= pv =========================
        float4 M[4], Kk[4], Cc[4];
        #pragma unroll
        for (int p = 0; p < 4; ++p) {
            M[p]  = make_float4(muL[c_l][4*p+0], muL[c_l][4*p+1], muL[c_l][4*p+2], muL[c_l][4*p+3]);
            Kk[p] = make_float4(KL[c_l][4*p+0],  KL[c_l][4*p+1],  KL[c_l][4*p+2],  KL[c_l][4*p+3]);
            Cc[p] = make_float4(CL[c_l][4*p+0],  CL[c_l][4*p+1],  CL[c_l][4*p+2],  CL[c_l][4*p+3]);
        }
        const float ap = aL[c_l];
        float* rowsO = rows_out + b * BKK;
        float* pw = psp;

        const float4* wp = WtB + m0 * 128;
        float4 w0 = wp[0], w1 = wp[32], w2 = wp[64], w3 = wp[96];
        #pragma unroll 1
        for (int i = 0; i < 9; ++i) {
            const int m = m0 + i;
            wp += 128;                               // i=8 -> slack row 288
            float4 nw0 = wp[0], nw1 = wp[32], nw2 = wp[64], nw3 = wp[96];
            float4 P0 = poseS4[m * 5 + 0];
            float4 P1 = poseS4[m * 5 + 1];
            float4 P2 = poseS4[m * 5 + 2];
            float4 P3 = poseS4[m * 5 + 3];
            float4 V0 = f4fma(w0.w, P3, f4fma(w0.z, P2, f4fma(w0.y, P1, f4mul(w0.x, P0))));
            float4 V1 = f4fma(w1.w, P3, f4fma(w1.z, P2, f4fma(w1.y, P1, f4mul(w1.x, P0))));
            float4 V2 = f4fma(w2.w, P3, f4fma(w2.z, P2, f4fma(w2.y, P1, f4mul(w2.x, P0))));
            float4 V3 = f4fma(w3.w, P3, f4fma(w3.z, P2, f4fma(w3.y, P1, f4mul(w3.x, P0))));

            float psv = 0.0f;
            {
                float4 t, g;
                t = make_float4(V0.x-M[0].x, V0.y-M[0].y, V0.z-M[0].z, V0.w-M[0].w);
                g = make_float4(fmaf(t.x*t.x, Kk[0].x, Cc[0].x), fmaf(t.y*t.y, Kk[0].y, Cc[0].y),
                                fmaf(t.z*t.z, Kk[0].z, Cc[0].z), fmaf(t.w*t.w, Kk[0].w, Cc[0].w));
                psv += ex2(g.x) + ex2(g.y) + ex2(g.z) + ex2(g.w);
                t = make_float4(V1.x-M[1].x, V1.y-M[1].y, V1.z-M[1].z, V1.w-M[1].w);
                g = make_float4(fmaf(t.x*t.x, Kk[1].x, Cc[1].x), fmaf(t.y*t.y, Kk[1].y, Cc[1].y),
                                fmaf(t.z*t.z, Kk[1].z, Cc[1].z), fmaf(t.w*t.w, Kk[1].w, Cc[1].w));
                psv += ex2(g.x) + ex2(g.y) + ex2(g.z) + ex2(g.w);
                t = make_float4(V2.x-M[2].x, V2.y-M[2].y, V2.z-M[2].z, V2.w-M[2].w);
                g = make_float4(fmaf(t.x*t.x, Kk[2].x, Cc[2].x), fmaf(t.y*t.y, Kk[2].y, Cc[2].y),
                                fmaf(t.z*t.z, Kk[2].z, Cc[2].z), fmaf(t.w*t.w, Kk[2].w, Cc[2].w));
                psv += ex2(g.x) + ex2(g.y) + ex2(g.z) + ex2(g.w);
                t = make_float4(V3.x-M[3].x, V3.y-M[3].y, V3.z-M[3].z, V3.w-M[3].w);
                g = make_float4(fmaf(t.x*t.x, Kk[3].x, Cc[3].x), fmaf(t.y*t.y, Kk[3].y, Cc[3].y),
                                fmaf(t.z*t.z, Kk[3].z, Cc[3].z), fmaf(t.w*t.w, Kk[3].w, Cc[3].w));
                psv += ex2(g.x) + ex2(g.y) + ex2(g.z) + ex2(g.w);
            }
            pw[0] = psv;                    // coalesced: lane-contiguous 256B/wave
            pw += 256;

            float rv = ap * psv;
            rv += __shfl_xor(rv, 1);
            rv += __shfl_xor(rv, 2);
            rv += __shfl_xor(rv, 4);
            if (c_l == 0)
                __hip_atomic_fetch_add(&rowsO[m], rv,
                                       __ATOMIC_RELAXED, __HIP_MEMORY_SCOPE_AGENT);
            w0 = nw0; w1 = nw1; w2 = nw2; w3 = nw3;
        }
    }
}

extern "C" void kernel_launch(void* const* d_in, const int* in_sizes, int n_in,
                              void* d_out, int out_size, void* d_ws, size_t ws_size,
                              hipStream_t stream) {
    const float* poses  = (const float*)d_in[0];
    const float* act    = (const float*)d_in[1];
    const float* W      = (const float*)d_in[2];
    const float* beta_v = (const float*)d_in[3];
    const float* beta_a = (const float*)d_in[4];
    const float* lam    = (const float*)d_in[5];
    float* out = (float*)d_out;
    float* ws  = (float*)d_ws;

    const int SZ = NB * CWW * HH;            // 147456
    float* Wt    = ws;                       // (288+1)*128 float4 = 147968 floats
    float* rows0 = Wt + 289 * 512;           // 2304
    float* rows1 = rows0 + NB * BKK;         // 2304
    float* aws0  = rows1 + NB * BKK;         // 9216
    float* aws1  = aws0 + NB * CWW;          // 9216
    float* psum  = aws1 + NB * CWW;          // 1152*2304 = 2654208 + 512 slack
    // total ~2.83M floats = 11.3 MB of ws

    wt_kernel<<<dim3(144), dim3(256), 0, stream>>>(
        (const float4*)W, (float4*)Wt, rows0);

    const float4* Wt4 = (const float4*)Wt;
    em_stage<0, false><<<dim3(NBLK), dim3(256), 0, stream>>>(
        poses, act, Wt4, beta_v, beta_a, lam,
        nullptr, rows0, nullptr, aws0, psum, nullptr, nullptr);
    em_stage<1, false><<<dim3(NBLK), dim3(256), 0, stream>>>(
        poses, act, Wt4, beta_v, beta_a, lam,
        rows0, rows1, aws0, aws1, psum, nullptr, nullptr);
    em_stage<1, true><<<dim3(NBLK), dim3(256), 0, stream>>>(
        poses, act, Wt4, beta_v, beta_a, lam,
        rows1, nullptr, aws1, nullptr, psum, out, out + SZ);
}